// Round 1
// baseline (85.415 us; speedup 1.0000x reference)
//
#include <hip/hip_runtime.h>
#include <math.h>

// Problem constants (fixed by the reference setup_inputs)
constexpr int B = 4;
constexpr int N = 8192;
constexpr int M = 8192;
constexpr int NPTS = B * N;   // 32768 xyz1 points
constexpr int MPTS = B * M;   // 32768 xyz2 points

constexpr int TPB = 256;              // threads per block
constexpr int PB  = 4;                // xyz1 points per thread
constexpr int PTS_PER_BLOCK = TPB * PB;   // 1024
constexpr int NB1 = N / PTS_PER_BLOCK;    // 8 point-blocks per batch
constexpr int MC  = 32;               // chunks over M
constexpr int CHUNK = M / MC;         // 256 xyz2 points per chunk (== TPB)

// ---------------------------------------------------------------------------
// Kernel 1: pack q = (-2x, -2y, -2z, |p|^2) per xyz2 point; init min array to
// +inf; zero the two scalar accumulators. (ws is re-poisoned to 0xAA before
// every launch, so everything we later read must be written here.)
// ---------------------------------------------------------------------------
__global__ __launch_bounds__(TPB) void prep_kernel(
    const float* __restrict__ xyz2, float4* __restrict__ q,
    unsigned* __restrict__ minarr, float* __restrict__ acc) {
  int i = blockIdx.x * TPB + threadIdx.x;
  if (i < MPTS) {
    float x = xyz2[3 * i + 0];
    float y = xyz2[3 * i + 1];
    float z = xyz2[3 * i + 2];
    q[i] = make_float4(-2.0f * x, -2.0f * y, -2.0f * z,
                       fmaf(x, x, fmaf(y, y, z * z)));
    minarr[i] = 0x7F800000u;  // +inf bits
  }
  if (i < 2) acc[i] = 0.0f;
}

// ---------------------------------------------------------------------------
// Kernel 2: main O(N*M) min. Each thread owns PB xyz1 points; block stages a
// CHUNK of q into LDS (broadcast reads, conflict-free); inner loop is
// 3 FMA + 1 min per pair. Partial mins merged across M-chunks with uint
// atomicMin (valid: d2 clamped >= 0, so uint order == float order).
// ---------------------------------------------------------------------------
__global__ __launch_bounds__(TPB) void chamfer_min_kernel(
    const float* __restrict__ xyz1, const float4* __restrict__ q,
    unsigned* __restrict__ minarr) {
  __shared__ float4 lq[CHUNK];

  const int t  = threadIdx.x;
  const int mc = blockIdx.x;  // M-chunk      0..MC-1
  const int pb = blockIdx.y;  // point-block  0..NB1-1
  const int b  = blockIdx.z;  // batch        0..B-1

  // Stage q chunk (CHUNK == TPB: one float4 per thread, coalesced 16B/lane)
  lq[t] = q[b * M + mc * CHUNK + t];

  // Load this thread's PB xyz1 points
  float x1[PB], y1[PB], z1[PB], smin[PB];
  const int base1 = b * N + pb * PTS_PER_BLOCK + t;
#pragma unroll
  for (int p = 0; p < PB; ++p) {
    int idx = base1 + p * TPB;
    x1[p] = xyz1[3 * idx + 0];
    y1[p] = xyz1[3 * idx + 1];
    z1[p] = xyz1[3 * idx + 2];
    smin[p] = INFINITY;
  }
  __syncthreads();

#pragma unroll 4
  for (int j = 0; j < CHUNK; ++j) {
    float4 v = lq[j];  // broadcast across wave
#pragma unroll
    for (int p = 0; p < PB; ++p) {
      // s = |p2|^2 - 2 * dot(p1, p2)   (n2 added after the min)
      float s = fmaf(x1[p], v.x, fmaf(y1[p], v.y, fmaf(z1[p], v.z, v.w)));
      smin[p] = fminf(smin[p], s);
    }
  }

#pragma unroll
  for (int p = 0; p < PB; ++p) {
    int idx = base1 + p * TPB;
    float n2 = fmaf(x1[p], x1[p], fmaf(y1[p], y1[p], z1[p] * z1[p]));
    float d2 = fmaxf(n2 + smin[p], 0.0f);  // clamp like the reference
    atomicMin(&minarr[idx], __float_as_uint(d2));
  }
}

// ---------------------------------------------------------------------------
// Kernel 3: d = sqrt(min d2); accumulate sum(d*w) and sum(w).
// ---------------------------------------------------------------------------
__global__ __launch_bounds__(TPB) void reduce_kernel(
    const unsigned* __restrict__ minarr, const float* __restrict__ w,
    float* __restrict__ acc) {
  int i = blockIdx.x * TPB + threadIdx.x;
  float d  = sqrtf(__uint_as_float(minarr[i]));
  float wi = w[i];
  float num = d * wi;
  float den = wi;

  // wave64 shuffle reduction
#pragma unroll
  for (int off = 32; off > 0; off >>= 1) {
    num += __shfl_down(num, off, 64);
    den += __shfl_down(den, off, 64);
  }

  __shared__ float snum[TPB / 64], sden[TPB / 64];
  int wid  = threadIdx.x >> 6;
  int lane = threadIdx.x & 63;
  if (lane == 0) { snum[wid] = num; sden[wid] = den; }
  __syncthreads();
  if (threadIdx.x == 0) {
    float a = 0.0f, c = 0.0f;
#pragma unroll
    for (int k = 0; k < TPB / 64; ++k) { a += snum[k]; c += sden[k]; }
    atomicAdd(&acc[0], a);
    atomicAdd(&acc[1], c);
  }
}

__global__ void finalize_kernel(const float* __restrict__ acc,
                                float* __restrict__ out) {
  out[0] = acc[0] / acc[1];
}

// ---------------------------------------------------------------------------
extern "C" void kernel_launch(void* const* d_in, const int* in_sizes, int n_in,
                              void* d_out, int out_size, void* d_ws,
                              size_t ws_size, hipStream_t stream) {
  const float* xyz1 = (const float*)d_in[0];  // [B,N,3]
  const float* xyz2 = (const float*)d_in[1];  // [B,M,3]
  const float* wts  = (const float*)d_in[2];  // [B,N]
  float* out = (float*)d_out;

  char* ws = (char*)d_ws;
  float4*   q      = (float4*)ws;                                   // 512 KB
  unsigned* minarr = (unsigned*)(ws + (size_t)MPTS * sizeof(float4));  // 128 KB
  float*    acc    = (float*)(ws + (size_t)MPTS * sizeof(float4)
                                 + (size_t)NPTS * sizeof(unsigned));   // 8 B

  hipLaunchKernelGGL(prep_kernel, dim3(MPTS / TPB), dim3(TPB), 0, stream,
                     xyz2, q, minarr, acc);
  hipLaunchKernelGGL(chamfer_min_kernel, dim3(MC, NB1, B), dim3(TPB), 0,
                     stream, xyz1, q, minarr);
  hipLaunchKernelGGL(reduce_kernel, dim3(NPTS / TPB), dim3(TPB), 0, stream,
                     minarr, wts, acc);
  hipLaunchKernelGGL(finalize_kernel, dim3(1), dim3(1), 0, stream, acc, out);
}